// Round 2
// baseline (9765.356 us; speedup 1.0000x reference)
//
#include <hip/hip_runtime.h>
#include <hip/hip_bf16.h>
#include <math.h>

#define Bz 64
#define Sz 256
#define Dz 256
#define Hz 512
#define FH 2048   // 4H
#define OH 1024   // 2H
#define Tz 48
#define EPSV 1e-5f

typedef __hip_bfloat16 bf16;

__device__ __forceinline__ float sigf(float x){ return 1.f/(1.f+expf(-x)); }
__device__ __forceinline__ float b2f(bf16 v){ return __bfloat162float(v); }

// ---- vector load helpers: 4 consecutive elements as float ----
__device__ __forceinline__ void load4f(const float* p, float v[4]) {
  float4 t = *(const float4*)p; v[0]=t.x; v[1]=t.y; v[2]=t.z; v[3]=t.w;
}
__device__ __forceinline__ void load4f(const bf16* p, float v[4]) {
  ushort4 t = *(const ushort4*)p;
  v[0] = __uint_as_float(((unsigned)t.x) << 16);
  v[1] = __uint_as_float(((unsigned)t.y) << 16);
  v[2] = __uint_as_float(((unsigned)t.z) << 16);
  v[3] = __uint_as_float(((unsigned)t.w) << 16);
}
__device__ __forceinline__ void storev(float* p, float v){ *p = v; }
__device__ __forceinline__ void storev(bf16* p, float v){ *p = __float2bfloat16(v); }

// out[c*R + r] = in[r*C + c]   (in: R x C), fp32
__global__ __launch_bounds__(256) void transpose_k(const float* __restrict__ in,
                                                   float* __restrict__ out, int R, int C)
{
  __shared__ float tile[32][33];
  int r0 = blockIdx.y*32, c0 = blockIdx.x*32;
  int tx = threadIdx.x & 31, tg = threadIdx.x >> 5;
  for (int i = tg; i < 32; i += 8) tile[i][tx] = in[(size_t)(r0+i)*C + c0+tx];
  __syncthreads();
  for (int i = tg; i < 32; i += 8) out[(size_t)(c0+i)*R + r0+tx] = tile[tx][i];
}

// C = A(MxK) * W(NxK)^T + b1 + b2, optional relu. 128x128x8 tiles, 8x8/thread.
template<typename TA, typename TC>
__global__ __launch_bounds__(256) void gemm_nt(
  const TA* __restrict__ A, const float* __restrict__ W,
  const float* __restrict__ b1, const float* __restrict__ b2,
  TC* __restrict__ Cv, int M, int N, int K, int relu)
{
  __shared__ float As[8][128];
  __shared__ float Ws[8][128];
  int tid = threadIdx.x;
  int tx = tid & 15, ty = tid >> 4;
  int m0 = blockIdx.y * 128, n0 = blockIdx.x * 128;
  int sr = tid >> 1;            // 0..127
  int sk = (tid & 1) * 4;       // 0 or 4
  const TA* Ap = A + (size_t)(m0 + sr) * K + sk;
  bool wok = (n0 + sr) < N;
  const float* Wp = W + (size_t)(wok ? (n0 + sr) : 0) * K + sk;
  float acc[8][8] = {};
  for (int k0 = 0; k0 < K; k0 += 8) {
    float av[4], wv[4];
    load4f(Ap, av);
    if (wok) load4f(Wp, wv); else { wv[0]=wv[1]=wv[2]=wv[3]=0.f; }
    Ap += 8; Wp += 8;
    __syncthreads();
    As[sk+0][sr]=av[0]; As[sk+1][sr]=av[1]; As[sk+2][sr]=av[2]; As[sk+3][sr]=av[3];
    Ws[sk+0][sr]=wv[0]; Ws[sk+1][sr]=wv[1]; Ws[sk+2][sr]=wv[2]; Ws[sk+3][sr]=wv[3];
    __syncthreads();
    #pragma unroll
    for (int kk = 0; kk < 8; kk++) {
      float a[8], w[8];
      *(float4*)&a[0] = *(const float4*)&As[kk][ty*8];
      *(float4*)&a[4] = *(const float4*)&As[kk][ty*8+4];
      *(float4*)&w[0] = *(const float4*)&Ws[kk][tx*8];
      *(float4*)&w[4] = *(const float4*)&Ws[kk][tx*8+4];
      #pragma unroll
      for (int i=0;i<8;i++)
        #pragma unroll
        for (int j=0;j<8;j++) acc[i][j] += a[i]*w[j];
    }
  }
  #pragma unroll
  for (int i=0;i<8;i++){
    int m = m0 + ty*8 + i;
    #pragma unroll
    for (int j=0;j<8;j++){
      int n = n0 + tx*8 + j;
      if (n < N){
        float v = acc[i][j];
        if (b1) v += b1[n];
        if (b2) v += b2[n];
        if (relu) v = fmaxf(v, 0.f);
        storev(&Cv[(size_t)m*N + n], v);
      }
    }
  }
}

// One timestep, both directions. Wt is Whh transposed: Wt[k*FH + n], n = g*H + j.
// grid = 256 blocks: dir(2) x jtile(8) x bgroup(16). thread: 4 batches x 4 gates x 1 j,
// K split in 4 quarters across the 4 waves, LDS-reduced; wave 0 does gates/epilogue.
__global__ __launch_bounds__(256) void lstm_step(
  const bf16* __restrict__ preF, const bf16* __restrict__ preB,
  const float* __restrict__ WtF, const float* __restrict__ WtB,
  const float* __restrict__ hFin, float* __restrict__ hFout, float* __restrict__ cF,
  const float* __restrict__ hBin, float* __restrict__ hBout, float* __restrict__ cB,
  bf16* __restrict__ out, int t)
{
  __shared__ float hs[Hz*4];          // [k][b], 8 KB
  __shared__ float red[3][64][17];
  int blk = blockIdx.x;
  int dir = blk & 1;
  int jt  = (blk >> 1) & 7;
  int bg  = blk >> 4;                 // 0..15
  const bf16* pre = dir ? preB : preF;
  const float* Wt  = dir ? WtB : WtF;
  const float* hin = dir ? hBin : hFin;
  float* hout = dir ? hBout : hFout;
  float* cst  = dir ? cB : cF;
  int colOff = dir ? Hz : 0;
  int tcur = dir ? (Sz-1 - t) : t;
  int tid = threadIdx.x;
  int b0 = bg*4;
  for (int idx = tid; idx < Hz*4; idx += 256) {
    int b = idx & 3, k = idx >> 2;
    hs[idx] = hin[(size_t)(b0+b)*Hz + k];
  }
  __syncthreads();
  int jj = tid & 63, kq = tid >> 6;
  int j = jt*64 + jj;
  float acc[4][4] = {};
  const float* wp = Wt + (size_t)(kq*128)*FH + j;
  const float4* hp = (const float4*)&hs[kq*128*4];
  #pragma unroll 4
  for (int k = 0; k < 128; k++) {
    float4 hv = hp[k];
    float w0 = wp[0];
    float w1 = wp[Hz];
    float w2 = wp[2*Hz];
    float w3 = wp[3*Hz];
    wp += FH;
    acc[0][0]+=w0*hv.x; acc[0][1]+=w0*hv.y; acc[0][2]+=w0*hv.z; acc[0][3]+=w0*hv.w;
    acc[1][0]+=w1*hv.x; acc[1][1]+=w1*hv.y; acc[1][2]+=w1*hv.z; acc[1][3]+=w1*hv.w;
    acc[2][0]+=w2*hv.x; acc[2][1]+=w2*hv.y; acc[2][2]+=w2*hv.z; acc[2][3]+=w2*hv.w;
    acc[3][0]+=w3*hv.x; acc[3][1]+=w3*hv.y; acc[3][2]+=w3*hv.z; acc[3][3]+=w3*hv.w;
  }
  if (kq > 0) {
    #pragma unroll
    for (int g=0; g<4; g++)
      #pragma unroll
      for (int b=0; b<4; b++) red[kq-1][jj][g*4+b] = acc[g][b];
  }
  __syncthreads();
  if (kq == 0) {
    #pragma unroll
    for (int q=0;q<3;q++)
      #pragma unroll
      for (int g=0;g<4;g++)
        #pragma unroll
        for (int b=0;b<4;b++) acc[g][b] += red[q][jj][g*4+b];
    #pragma unroll
    for (int b=0;b<4;b++) {
      const bf16* pb = pre + ((size_t)(b0+b)*Sz + tcur)*FH;
      float gi = acc[0][b] + b2f(pb[j]);
      float gf = acc[1][b] + b2f(pb[Hz + j]);
      float gg = acc[2][b] + b2f(pb[2*Hz + j]);
      float go = acc[3][b] + b2f(pb[3*Hz + j]);
      size_t ci = (size_t)(b0+b)*Hz + j;
      float c = sigf(gf)*cst[ci] + sigf(gi)*tanhf(gg);
      float h = sigf(go)*tanhf(c);
      cst[ci] = c;
      hout[ci] = h;
      out[((size_t)(b0+b)*Sz + tcur)*OH + colOff + j] = __float2bfloat16(h);
    }
  }
}

__global__ __launch_bounds__(256) void bn_k(const bf16* __restrict__ x, bf16* __restrict__ y,
  const float* __restrict__ gamma, const float* __restrict__ beta,
  const float* __restrict__ mean, const float* __restrict__ var)
{
  size_t n = (size_t)Bz*Sz*OH;
  for (size_t i = (size_t)blockIdx.x*256 + threadIdx.x; i < n; i += (size_t)gridDim.x*256) {
    int c = (int)(i & (OH-1));
    float v = b2f(x[i]);
    y[i] = __float2bfloat16((v - mean[c]) * (gamma[c] * rsqrtf(var[c] + EPSV)) + beta[c]);
  }
}

__global__ __launch_bounds__(64) void crf_k(const float* __restrict__ em, const int* __restrict__ tags,
  const float* __restrict__ start, const float* __restrict__ endv, const float* __restrict__ trans,
  float* __restrict__ result)
{
  __shared__ float tr[Tz*Tz];
  __shared__ float alpha[2][Tz];
  int b = blockIdx.x, tid = threadIdx.x;
  for (int i = tid; i < Tz*Tz; i += 64) tr[i] = trans[i];
  // numerator (gold path score)
  float np = 0.f;
  for (int t = tid; t < Sz; t += 64) {
    int tg = tags[b*Sz + t];
    np += em[((size_t)b*Sz + t)*Tz + tg];
    if (t+1 < Sz) np += trans[tg*Tz + tags[b*Sz + t + 1]];
  }
  #pragma unroll
  for (int off = 32; off; off >>= 1) np += __shfl_down(np, off);
  float num = 0.f;
  if (tid == 0) num = np + start[tags[b*Sz]] + endv[tags[b*Sz + Sz-1]];
  if (tid < Tz) alpha[0][tid] = start[tid] + em[((size_t)b*Sz)*Tz + tid];
  __syncthreads();
  int cur = 0;
  for (int t = 1; t < Sz; t++) {
    if (tid < Tz) {
      float m = -1e30f;
      for (int i = 0; i < Tz; i++) m = fmaxf(m, alpha[cur][i] + tr[i*Tz + tid]);
      float sum = 0.f;
      for (int i = 0; i < Tz; i++) sum += expf(alpha[cur][i] + tr[i*Tz + tid] - m);
      alpha[1-cur][tid] = m + logf(sum) + em[((size_t)b*Sz + t)*Tz + tid];
    }
    cur ^= 1;
    __syncthreads();
  }
  float a = (tid < Tz) ? alpha[cur][tid] + endv[tid] : -1e30f;
  float m = a;
  #pragma unroll
  for (int off = 32; off; off >>= 1) m = fmaxf(m, __shfl_down(m, off));
  m = __shfl(m, 0);
  float e = (tid < Tz) ? expf(a - m) : 0.f;
  #pragma unroll
  for (int off = 32; off; off >>= 1) e += __shfl_down(e, off);
  if (tid == 0) result[b] = num - (m + logf(e));
}

__global__ __launch_bounds__(64) void finalize_k(const float* __restrict__ result, float* __restrict__ outp)
{
  float v = result[threadIdx.x];
  #pragma unroll
  for (int off = 32; off; off >>= 1) v += __shfl_down(v, off);
  if (threadIdx.x == 0) outp[0] = -(v * (1.f/64.f));
}

extern "C" void kernel_launch(void* const* d_in, const int* in_sizes, int n_in,
                              void* d_out, int out_size, void* d_ws, size_t ws_size,
                              hipStream_t stream)
{
  (void)in_sizes; (void)n_in; (void)out_size; (void)ws_size;
  const float* inputs = (const float*)d_in[0];
  const int*   tags   = (const int*)d_in[1];
  const float* Wih[2][2] = {{(const float*)d_in[2],  (const float*)d_in[6]},
                            {(const float*)d_in[10], (const float*)d_in[14]}};
  const float* Whh[2][2] = {{(const float*)d_in[3],  (const float*)d_in[7]},
                            {(const float*)d_in[11], (const float*)d_in[15]}};
  const float* bih[2][2] = {{(const float*)d_in[4],  (const float*)d_in[8]},
                            {(const float*)d_in[12], (const float*)d_in[16]}};
  const float* bhh[2][2] = {{(const float*)d_in[5],  (const float*)d_in[9]},
                            {(const float*)d_in[13], (const float*)d_in[17]}};
  const float* bn_gamma = (const float*)d_in[18];
  const float* bn_beta  = (const float*)d_in[19];
  const float* bn_mean  = (const float*)d_in[20];
  const float* bn_var   = (const float*)d_in[21];
  const float* fc1_w = (const float*)d_in[22];
  const float* fc1_b = (const float*)d_in[23];
  const float* fc2_w = (const float*)d_in[24];
  const float* fc2_b = (const float*)d_in[25];
  const float* fc3_w = (const float*)d_in[26];
  const float* fc3_b = (const float*)d_in[27];
  const float* crf_start = (const float*)d_in[28];
  const float* crf_end   = (const float*)d_in[29];
  const float* crf_trans = (const float*)d_in[30];

  const size_t M = (size_t)Bz*Sz;
  // ---- workspace layout (bytes), ~214 MB total ----
  char* p = (char*)d_ws;
  auto alloc = [&](size_t bytes) { char* r = p; p += (bytes + 255) & ~(size_t)255; return r; };
  bf16*  preF = (bf16*) alloc(M*FH*sizeof(bf16));      // 64 MB
  bf16*  preB = (bf16*) alloc(M*FH*sizeof(bf16));      // 64 MB
  bf16*  x0   = (bf16*) alloc(M*OH*sizeof(bf16));      // 32 MB
  bf16*  x1   = (bf16*) alloc(M*OH*sizeof(bf16));      // 32 MB
  float* WtF  = (float*)alloc((size_t)FH*Hz*sizeof(float)); // 4 MB
  float* WtB  = (float*)alloc((size_t)FH*Hz*sizeof(float)); // 4 MB
  float* st   = (float*)alloc(6*(size_t)Bz*Hz*sizeof(float)); // 0.75 MB
  float* em   = (float*)alloc(M*Tz*sizeof(float));     // 3 MB
  float* result = (float*)alloc(Bz*sizeof(float));
  // FC intermediates overlay the (dead after recurrence) pre buffers:
  bf16* fc1o = (bf16*)preF;   // M*Hz bf16 = 16 MB, fits in preF's 64 MB
  bf16* fc2o = (bf16*)preB;   // M*256 bf16 = 8 MB
  float* hF0 = st;
  float* hF1 = st + (size_t)Bz*Hz;
  float* hB0 = st + 2*(size_t)Bz*Hz;
  float* hB1 = st + 3*(size_t)Bz*Hz;
  float* cF  = st + 4*(size_t)Bz*Hz;
  float* cB  = st + 5*(size_t)Bz*Hz;

  dim3 tb(256);

  for (int layer = 0; layer < 2; layer++) {
    transpose_k<<<dim3(Hz/32, FH/32), tb, 0, stream>>>(Whh[layer][0], WtF, FH, Hz);
    transpose_k<<<dim3(Hz/32, FH/32), tb, 0, stream>>>(Whh[layer][1], WtB, FH, Hz);
    hipMemsetAsync(st, 0, 6*(size_t)Bz*Hz*sizeof(float), stream);
    if (layer == 0) {
      gemm_nt<float,bf16><<<dim3(FH/128, M/128), tb, 0, stream>>>(inputs, Wih[0][0], bih[0][0], bhh[0][0], preF, M, FH, Dz, 0);
      gemm_nt<float,bf16><<<dim3(FH/128, M/128), tb, 0, stream>>>(inputs, Wih[0][1], bih[0][1], bhh[0][1], preB, M, FH, Dz, 0);
    } else {
      gemm_nt<bf16,bf16><<<dim3(FH/128, M/128), tb, 0, stream>>>(x0, Wih[1][0], bih[1][0], bhh[1][0], preF, M, FH, OH, 0);
      gemm_nt<bf16,bf16><<<dim3(FH/128, M/128), tb, 0, stream>>>(x0, Wih[1][1], bih[1][1], bhh[1][1], preB, M, FH, OH, 0);
    }
    bf16* outb = layer ? x1 : x0;
    for (int t = 0; t < Sz; t++) {
      const float* hFi = (t & 1) ? hF1 : hF0; float* hFo = (t & 1) ? hF0 : hF1;
      const float* hBi = (t & 1) ? hB1 : hB0; float* hBo = (t & 1) ? hB0 : hB1;
      lstm_step<<<256, tb, 0, stream>>>(preF, preB, WtF, WtB, hFi, hFo, cF, hBi, hBo, cB, outb, t);
    }
  }
  // BN(x1) -> x0 (bf16)
  bn_k<<<2048, tb, 0, stream>>>(x1, x0, bn_gamma, bn_beta, bn_mean, bn_var);
  // fc1: (M,1024)->(M,512) relu
  gemm_nt<bf16,bf16><<<dim3(Hz/128, M/128), tb, 0, stream>>>(x0, fc1_w, fc1_b, nullptr, fc1o, M, Hz, OH, 1);
  // fc2: (M,512)->(M,256) relu
  gemm_nt<bf16,bf16><<<dim3(256/128, M/128), tb, 0, stream>>>(fc1o, fc2_w, fc2_b, nullptr, fc2o, M, 256, Hz, 1);
  // fc3: (M,256)->(M,48) -> em (fp32)
  gemm_nt<bf16,float><<<dim3(1, M/128), tb, 0, stream>>>(fc2o, fc3_w, fc3_b, nullptr, em, M, Tz, 256, 0);
  // CRF per batch row
  crf_k<<<Bz, 64, 0, stream>>>(em, tags, crf_start, crf_end, crf_trans, result);
  finalize_k<<<1, 64, 0, stream>>>(result, (float*)d_out);
}